// Round 3
// baseline (94.848 us; speedup 1.0000x reference)
//
#include <hip/hip_runtime.h>

// CooccurrenceMatrix: C[b,r,s] = sum_{i,j} [a[b,r,i]==a[b,s,j] & mr_i>0 & ms_j>0] * K[i,j]
//                              / (valid_r * valid_s + 1e-8)
//
// R2: line-touch + bank-conflict elimination.
//  - Cooperative coalesced staging of batch b's a+mask (20 KB contiguous) via
//    int4/float4 (16 lines per wave-instr vs 64 for the strided per-row loads).
//  - code[s][j] = (m>0 ? a : 20), rows padded to 21 words (21 coprime 32 ->
//    conflict-free row reads). h has 21 rows (row 20 = zeros) so phase 2 is a
//    branchless gather: acc += h[code*21 + j].
//  - valid[s] accumulated with LDS float atomics during staging.
// One block per (b,r): 128 threads, thread t computes C[b,r,t].

#define BB 16
#define WW 128
#define LL 20
#define PL 21              // padded row stride (words), coprime with 32 banks
#define HR 21              // h rows: 20 values + zero row for masked slots

__global__ __launch_bounds__(128) void coocc_kernel(
    const int*   __restrict__ a,     // [B,W,L] int32
    const float* __restrict__ mask,  // [B,W,L] f32
    const float* __restrict__ kern,  // [L,L]   f32
    float*       __restrict__ out)   // [B,W,W] f32
{
    __shared__ int   code [WW * PL];   // [s][j] padded, value 20 = masked
    __shared__ float h    [HR * PL];   // [v][j] padded, row 20 stays zero
    __shared__ float valid[WW];

    const int t   = threadIdx.x;
    const int bid = blockIdx.x;      // = b*W + r
    const int b   = bid >> 7;
    const int r   = bid & (WW - 1);

    // ---- hoisted global loads, all coalesced ----
    // batch-b block: 2560 ints / 2560 floats = 640 int4/float4, 5 per thread
    const int4*   ap = (const int4*)  (a    + b * (WW * LL));
    const float4* mp = (const float4*)(mask + b * (WW * LL));
    int4   av[5];
    float4 mv[5];
    #pragma unroll
    for (int q = 0; q < 5; ++q) {
        av[q] = ap[q * 128 + t];
        mv[q] = mp[q * 128 + t];
    }
    // kernel matrix: 400 floats, coalesced; pad tail with 0
    float kv[4];
    #pragma unroll
    for (int q = 0; q < 4; ++q) {
        const int e = t + q * 128;
        kv[q] = (e < LL * LL) ? kern[e] : 0.f;
    }

    // ---- zero h (441 words) and valid (128 words) ----
    #pragma unroll
    for (int q = 0; q < 4; ++q) {
        const int e = t + q * 128;
        if (e < HR * PL) h[e] = 0.f;
    }
    valid[t] = 0.f;
    __syncthreads();

    // ---- staging: scatter codes into padded LDS, accumulate valid ----
    #pragma unroll
    for (int q = 0; q < 5; ++q) {
        const int   c0    = (q * 128 + t) * 4;          // first element of chunk
        const int   aa[4] = {av[q].x, av[q].y, av[q].z, av[q].w};
        const float mm[4] = {mv[q].x, mv[q].y, mv[q].z, mv[q].w};
        #pragma unroll
        for (int k = 0; k < 4; ++k) {
            const int e   = c0 + k;
            const int row = e / LL;
            const int col = e - row * LL;
            code[row * PL + col] = (mm[k] > 0.f) ? aa[k] : LL;
            atomicAdd(&valid[row], mm[k]);
        }
    }
    __syncthreads();

    // ---- phase 1: scatter h[v*PL + j] += K[i*LL + j] for r's row ----
    #pragma unroll
    for (int q = 0; q < 4; ++q) {
        const int e = t + q * 128;
        if (e < LL * LL) {
            const int i = e / LL;
            const int j = e - i * LL;
            const int v = code[r * PL + i];     // broadcast read
            if (v < LL) atomicAdd(&h[v * PL + j], kv[q]);
        }
    }
    __syncthreads();

    // ---- phase 2: thread t = s; branchless gather (masked -> h row 20 = 0) ----
    float acc = 0.f;
    #pragma unroll
    for (int j = 0; j < LL; ++j) {
        const int c = code[t * PL + j];         // conflict-free (21 coprime 32)
        acc += h[c * PL + j];
    }
    const float vr = valid[r];                  // broadcast
    const float vs = valid[t];                  // 2-way, free
    out[bid * WW + t] = acc / (vr * vs + 1e-8f);
}

extern "C" void kernel_launch(void* const* d_in, const int* in_sizes, int n_in,
                              void* d_out, int out_size, void* d_ws, size_t ws_size,
                              hipStream_t stream) {
    const int*   a    = (const int*)  d_in[0];  // anonymized_nodes [B,W,L]
    const float* mask = (const float*)d_in[1];  // walk_masks       [B,W,L]
    const float* kern = (const float*)d_in[2];  // kernel           [L,L]
    float*       out  = (float*)d_out;          // [B,W,W]

    coocc_kernel<<<BB * WW, 128, 0, stream>>>(a, mask, kern, out);
}

// Round 4
// 60.643 us; speedup vs baseline: 1.5640x; 1.5640x over previous
//
#include <hip/hip_runtime.h>

// CooccurrenceMatrix: C[b,r,s] = sum_{i,j} [a[b,r,i]==a[b,s,j] & mr_i>0 & ms_j>0] * K[i,j]
//                              / (valid_r * valid_s + 1e-8)
//
// R3: ZERO LDS atomics. R2 post-mortem: __shared__ float atomicAdd lowers to a
// CAS retry loop (no -munsafe-fp-atomics), and contended valid[] atomics became
// ~10K-cycle latency chains (VALUBusy 2.6%, 41 us kernel). Replacement:
//  - phase 1 ownership decomposition: thread t<105 owns h[v][j0..j0+3]
//    (v=t/5, j0=4*(t%5)); 20-iter loop of broadcast code_r read +
//    ds_read_b128 of K row chunk + cmp + 4 select-adds, accumulated in
//    REGISTERS, each h slot written exactly once (sentinel row v=20 -> 0).
//  - phase 2: own s-row kept in registers (int4/float4 x5), 20 branchless
//    gathers h[c*21+j] (21 coprime 32 -> ~3-way banks, near-free).
//  - valid_r via wave-0 shuffle reduce; valid_s summed in registers.
// One block per (b,r): 128 threads, thread t computes C[b,r,t].

#define BB 16
#define WW 128
#define LL 20
#define PL 21              // padded h row stride (words), coprime with 32 banks
#define NV 21              // h rows: values 0..19 + zero sentinel row 20

__global__ __launch_bounds__(128) void coocc_kernel(
    const int*   __restrict__ a,     // [B,W,L] int32
    const float* __restrict__ mask,  // [B,W,L] f32
    const float* __restrict__ kern,  // [L,L]   f32
    float*       __restrict__ out)   // [B,W,W] f32
{
    __shared__ float K_lds[LL * LL];   // 400 f32, rows 16B-aligned (20 words)
    __shared__ float h[NV * PL];       // 441 f32, every slot written by owner
    __shared__ int   code_r[LL];       // r-row codes, 20 = masked
    __shared__ float vr_sh;

    const int t   = threadIdx.x;
    const int bid = blockIdx.x;        // = b*W + r
    const int b   = bid >> 7;

    // ---- own s-row (s = t) into registers; 16B aligned (80B rows) ----
    const int base = (b * WW + t) * LL;
    int4   av[5];
    float4 mv[5];
    const int4*   ap = (const int4*)  (a    + base);
    const float4* mp = (const float4*)(mask + base);
    #pragma unroll
    for (int q = 0; q < 5; ++q) { av[q] = ap[q]; mv[q] = mp[q]; }

    // ---- stage K into LDS (coalesced, one-time) ----
    #pragma unroll
    for (int q = 0; q < 4; ++q) {
        const int e = t + q * 128;
        if (e < LL * LL) K_lds[e] = kern[e];
    }

    // ---- r-row codes + valid_r (wave-0 shuffle reduce, no atomics) ----
    float mr = 0.f;
    if (t < LL) {
        const int   va = a[bid * LL + t];
        const float mm = mask[bid * LL + t];
        code_r[t] = (mm > 0.f) ? va : LL;
        mr = mm;
    }
    if (t < 64) {                      // lanes >= 20 contribute 0
        float v = mr;
        #pragma unroll
        for (int off = 32; off; off >>= 1) v += __shfl_xor(v, off, 64);
        if (t == 0) vr_sh = v;
    }
    __syncthreads();

    // ---- phase 1: thread t<105 owns (v = t/5, j0 = 4*(t%5)) ----
    if (t < 105) {
        const int v  = t / 5;
        const int j0 = (t - v * 5) * 4;
        float a0 = 0.f, a1 = 0.f, a2 = 0.f, a3 = 0.f;
        #pragma unroll
        for (int i = 0; i < LL; ++i) {
            const int    cr = code_r[i];                       // broadcast
            const float4 kk = *(const float4*)&K_lds[i * LL + j0];  // b128
            const float  f  = (cr == v) ? 1.f : 0.f;
            a0 += f * kk.x; a1 += f * kk.y; a2 += f * kk.z; a3 += f * kk.w;
        }
        const float z = (v < LL) ? 1.f : 0.f;   // sentinel row 20 -> zeros
        h[v * PL + j0 + 0] = z * a0;
        h[v * PL + j0 + 1] = z * a1;
        h[v * PL + j0 + 2] = z * a2;
        h[v * PL + j0 + 3] = z * a3;
    }
    __syncthreads();

    // ---- phase 2: branchless gather from padded h ----
    const float vr = vr_sh;
    float acc = 0.f, vs = 0.f;
    #pragma unroll
    for (int q = 0; q < 5; ++q) {
        const int   aa[4] = {av[q].x, av[q].y, av[q].z, av[q].w};
        const float mm[4] = {mv[q].x, mv[q].y, mv[q].z, mv[q].w};
        #pragma unroll
        for (int k = 0; k < 4; ++k) {
            const int j = q * 4 + k;
            vs += mm[k];
            const int c = (mm[k] > 0.f) ? aa[k] : LL;
            acc += h[c * PL + j];
        }
    }
    out[bid * WW + t] = acc / (vr * vs + 1e-8f);
}

extern "C" void kernel_launch(void* const* d_in, const int* in_sizes, int n_in,
                              void* d_out, int out_size, void* d_ws, size_t ws_size,
                              hipStream_t stream) {
    const int*   a    = (const int*)  d_in[0];  // anonymized_nodes [B,W,L]
    const float* mask = (const float*)d_in[1];  // walk_masks       [B,W,L]
    const float* kern = (const float*)d_in[2];  // kernel           [L,L]
    float*       out  = (float*)d_out;          // [B,W,W]

    coocc_kernel<<<BB * WW, 128, 0, stream>>>(a, mask, kern, out);
}

// Round 5
// 59.954 us; speedup vs baseline: 1.5820x; 1.0115x over previous
//
#include <hip/hip_runtime.h>

// CooccurrenceMatrix: C[b,r,s] = sum_{i,j} [a[b,r,i]==a[b,s,j] & mr_i>0 & ms_j>0] * K[i,j]
//                              / (valid_r * valid_s + 1e-8)
//
// R4: line-touch + phase-1 LDS elimination (R3 ~7.1 us over the ~53.5 us
// harness floor; model says strided per-row loads = ~4 us of L1 line-touches,
// phase-1 LDS reads = ~2.4 us).
//  - Coalesced staging: batch b's a+mask loaded stride-1 int4/float4
//    (4 lines/instr vs 64 for row-strided), converted in-flight to byte-packed
//    codes (4 codes/word, code 20 = masked) + per-chunk mask partial sums,
//    stored flat-by-chunk in LDS (stride-1, conflict-free). Row readback is
//    stride-5 (5 coprime 32 -> 2-way = free). valid_* from 5 partial sums.
//  - Phase 1 (owners t<105: v=t/5, j0=4*(t%5)): r-codes in 5 packed regs
//    (bfe unpack), K via global dwordx4 (L1-broadcast, 5 lines/wave), h
//    written once per slot. ZERO LDS reads inside the loop, no atomics.
//  - Phase 2: gather h[c*21+j]; 21*c mod 32 distinct for all c in [0,20]
//    -> exactly conflict-free.
// One block per (b,r): 128 threads, thread t computes C[b,r,t].

#define BB 16
#define WW 128
#define LL 20
#define PL 21              // h row stride; 21c mod 32 distinct for c=0..20
#define NCH (WW * LL / 4)  // 640 int4 chunks per batch

__global__ __launch_bounds__(128) void coocc_kernel(
    const int*   __restrict__ a,     // [B,W,L] int32
    const float* __restrict__ mask,  // [B,W,L] f32
    const float* __restrict__ kern,  // [L,L]   f32
    float*       __restrict__ out)   // [B,W,W] f32
{
    __shared__ unsigned int code_pack[NCH];  // 2.5 KB: 4 codes/word, flat by chunk
    __shared__ float        msum[NCH];       // 2.5 KB: per-chunk mask partial sums
    __shared__ float        h[PL * PL];      // 441 f32: values 0..19 + zero row 20

    const int t   = threadIdx.x;
    const int bid = blockIdx.x;        // = b*W + r
    const int b   = bid >> 7;
    const int r   = bid & (WW - 1);

    // ---- coalesced staging of batch b (chunk e = 4 consecutive j in row e/5) ----
    const int4*   ap = (const int4*)  (a    + b * (WW * LL));
    const float4* mp = (const float4*)(mask + b * (WW * LL));
    #pragma unroll
    for (int q = 0; q < 5; ++q) {
        const int    e  = q * 128 + t;
        const int4   aa = ap[e];
        const float4 mm = mp[e];
        const unsigned int c0 = (mm.x > 0.f) ? (unsigned)aa.x : LL;
        const unsigned int c1 = (mm.y > 0.f) ? (unsigned)aa.y : LL;
        const unsigned int c2 = (mm.z > 0.f) ? (unsigned)aa.z : LL;
        const unsigned int c3 = (mm.w > 0.f) ? (unsigned)aa.w : LL;
        code_pack[e] = c0 | (c1 << 8) | (c2 << 16) | (c3 << 24);
        msum[e]      = (mm.x + mm.y) + (mm.z + mm.w);
    }
    __syncthreads();

    // ---- row readback: own s-row (stride-5, 2-way = free) + r-row (broadcast) ----
    unsigned int cs[5], cr[5];
    float vs = 0.f, vr = 0.f;
    #pragma unroll
    for (int k = 0; k < 5; ++k) {
        cs[k] = code_pack[t * 5 + k];
        vs   += msum[t * 5 + k];
        cr[k] = code_pack[r * 5 + k];
        vr   += msum[r * 5 + k];
    }

    // ---- phase 1: owner t<105 builds h[v][j0..j0+3]; no LDS reads in loop ----
    if (t < 105) {
        const int v  = t / 5;
        const int j0 = (t - v * 5) * 4;
        float a0 = 0.f, a1 = 0.f, a2 = 0.f, a3 = 0.f;
        if (v < LL) {
            #pragma unroll
            for (int i = 0; i < LL; ++i) {
                const int    cri = (cr[i >> 2] >> ((i & 3) * 8)) & 0xff;
                const float4 kk  = *(const float4*)(kern + i * LL + j0); // L1-broadcast
                const float  f   = (cri == v) ? 1.f : 0.f;
                a0 += f * kk.x; a1 += f * kk.y; a2 += f * kk.z; a3 += f * kk.w;
            }
        }
        h[v * PL + j0 + 0] = a0;   // v==20 writes the zero sentinel row
        h[v * PL + j0 + 1] = a1;
        h[v * PL + j0 + 2] = a2;
        h[v * PL + j0 + 3] = a3;
    }
    __syncthreads();

    // ---- phase 2: conflict-free branchless gather ----
    float acc = 0.f;
    #pragma unroll
    for (int j = 0; j < LL; ++j) {
        const int c = (cs[j >> 2] >> ((j & 3) * 8)) & 0xff;
        acc += h[c * PL + j];
    }
    out[bid * WW + t] = acc / (vr * vs + 1e-8f);
}

extern "C" void kernel_launch(void* const* d_in, const int* in_sizes, int n_in,
                              void* d_out, int out_size, void* d_ws, size_t ws_size,
                              hipStream_t stream) {
    const int*   a    = (const int*)  d_in[0];  // anonymized_nodes [B,W,L]
    const float* mask = (const float*)d_in[1];  // walk_masks       [B,W,L]
    const float* kern = (const float*)d_in[2];  // kernel           [L,L]
    float*       out  = (float*)d_out;          // [B,W,W]

    coocc_kernel<<<BB * WW, 128, 0, stream>>>(a, mask, kern, out);
}